// Round 2
// baseline (1437.403 us; speedup 1.0000x reference)
//
#include <hip/hip_runtime.h>
#include <math.h>

#define B_ 2
#define T_ 2048
#define D_ 1024
#define H_ 16
#define DH_ 64
#define NROWS (B_ * T_)        // 4096
#define QKV_N (3 * H_ * DH_)   // 3072

// ---------------------------------------------------------------------------
// fp32 tiled GEMM: C[M,N] = A[M,K] @ B[K,N], all row-major.
// 128x128 tile, BK=16, 256 threads, 8x8 micro-tile per thread (split 4+4 at
// stride 64 so LDS frag reads alias banks at most 2-way, which is free).
// Next-tile global loads are prefetched into registers right after the
// barrier so HBM latency hides under the 1024 FMAs/thread of tile compute.
// Requires M%128==0, N%128==0, K%16==0 (true for all three calls).
// ---------------------------------------------------------------------------
__global__ __launch_bounds__(256)
void gemm_f32(const float* __restrict__ A, const float* __restrict__ B,
              float* __restrict__ C, int M, int N, int K)
{
    __shared__ float As[16][128];   // transposed A tile: As[k][m]
    __shared__ float Bs[16][128];   // Bs[k][n]

    const int tid = threadIdx.x;
    const int bm = blockIdx.y * 128;
    const int bn = blockIdx.x * 128;
    const int tx = tid & 15;        // 0..15 -> col group
    const int ty = tid >> 4;        // 0..15 -> row group
    // A-tile cooperative load: rows ar, ar+64; cols ac..ac+3
    const int ar = tid >> 2;        // 0..63
    const int ac = (tid & 3) << 2;  // 0,4,8,12
    // B-tile cooperative load: rows br, br+8; cols bc..bc+3
    const int br = tid >> 5;        // 0..7
    const int bc = (tid & 31) << 2; // 0..124

    const float* Ar0 = A + (size_t)(bm + ar) * K + ac;
    const float* Ar1 = A + (size_t)(bm + ar + 64) * K + ac;
    const float* Br0 = B + (size_t)br * N + bn + bc;
    const float* Br1 = B + (size_t)(br + 8) * N + bn + bc;

    float acc[8][8];
#pragma unroll
    for (int i = 0; i < 8; ++i)
#pragma unroll
        for (int j = 0; j < 8; ++j) acc[i][j] = 0.f;

    // prologue: tile 0 -> registers
    float4 a0 = *(const float4*)(Ar0);
    float4 a1 = *(const float4*)(Ar1);
    float4 b0 = *(const float4*)(Br0);
    float4 b1 = *(const float4*)(Br1);

    for (int k0 = 0; k0 < K; k0 += 16) {
        // publish current tile to LDS
        As[ac + 0][ar] = a0.x; As[ac + 1][ar] = a0.y;
        As[ac + 2][ar] = a0.z; As[ac + 3][ar] = a0.w;
        As[ac + 0][ar + 64] = a1.x; As[ac + 1][ar + 64] = a1.y;
        As[ac + 2][ar + 64] = a1.z; As[ac + 3][ar + 64] = a1.w;
        *(float4*)&Bs[br][bc] = b0;
        *(float4*)&Bs[br + 8][bc] = b1;
        __syncthreads();

        // prefetch next tile (clamped index: always in-bounds, no divergence;
        // last iteration redundantly re-reads tile 0 from cache)
        const int kn = (k0 + 16 < K) ? (k0 + 16) : 0;
        a0 = *(const float4*)(Ar0 + kn);
        a1 = *(const float4*)(Ar1 + kn);
        b0 = *(const float4*)(Br0 + (size_t)kn * N);
        b1 = *(const float4*)(Br1 + (size_t)kn * N);

#pragma unroll
        for (int kk = 0; kk < 16; ++kk) {
            float4 a0v = *(const float4*)&As[kk][ty * 4];
            float4 a1v = *(const float4*)&As[kk][64 + ty * 4];
            float4 b0v = *(const float4*)&Bs[kk][tx * 4];
            float4 b1v = *(const float4*)&Bs[kk][64 + tx * 4];
            float av[8] = {a0v.x, a0v.y, a0v.z, a0v.w, a1v.x, a1v.y, a1v.z, a1v.w};
            float bv[8] = {b0v.x, b0v.y, b0v.z, b0v.w, b1v.x, b1v.y, b1v.z, b1v.w};
#pragma unroll
            for (int i = 0; i < 8; ++i)
#pragma unroll
                for (int j = 0; j < 8; ++j)
                    acc[i][j] = fmaf(av[i], bv[j], acc[i][j]);
        }
        __syncthreads();
    }

#pragma unroll
    for (int i = 0; i < 8; ++i) {
        const int row = bm + ((i < 4) ? (ty * 4 + i) : (64 + ty * 4 + (i - 4)));
        float4 c0 = make_float4(acc[i][0], acc[i][1], acc[i][2], acc[i][3]);
        float4 c1 = make_float4(acc[i][4], acc[i][5], acc[i][6], acc[i][7]);
        *(float4*)(C + (size_t)row * N + bn + tx * 4) = c0;
        *(float4*)(C + (size_t)row * N + bn + 64 + tx * 4) = c1;
    }
}

// ---------------------------------------------------------------------------
// Flash-style causal attention, fp32.
// Grid: (T/64, H, B). Block: 256 threads = 64 queries x 4 lanes.
// Each lane owns a 16-wide slice of DH; scores reduced via 2x shfl_xor.
// Next K/V tile prefetched into registers while current tile computes.
// qkv layout: [b, t, 3, H, DH] flattened (row stride 3*H*DH = 3072).
// out layout: [b, t, H, DH] (row stride 1024) -> feeds the Wo GEMM directly.
// ---------------------------------------------------------------------------
__global__ __launch_bounds__(256)
void attn_f32(const float* __restrict__ qkv, const float* __restrict__ mask,
              float* __restrict__ out)
{
    __shared__ float Ks[64][64];
    __shared__ float Vs[64][64];
    __shared__ float ms[64];

    const int tid = threadIdx.x;
    const int b = blockIdx.z;
    const int h = blockIdx.y;
    const int qb = blockIdx.x * 64;
    const int qq = tid >> 2;          // query within block (0..63)
    const int dpart = (tid & 3) * 16; // this lane's DH slice
    const int qi = qb + qq;
    const float scale = 0.125f;       // DH^-0.5

    // Q slice -> registers
    float4 qreg[4];
    {
        const float* qrow = qkv + (size_t)(b * T_ + qi) * QKV_N + h * DH_ + dpart;
#pragma unroll
        for (int u = 0; u < 4; ++u) qreg[u] = *(const float4*)(qrow + u * 4);
    }

    float4 acc[4];
#pragma unroll
    for (int u = 0; u < 4; ++u) acc[u] = make_float4(0.f, 0.f, 0.f, 0.f);
    float mrun = -INFINITY, lrun = 0.f;

    // cooperative K/V tile load indices
    const int lr = tid >> 2;          // row 0..63
    const int lc = (tid & 3) * 16;    // 16 floats per thread

    // prologue: tile 0 -> registers
    const float* kbase = qkv + (size_t)(b * T_ + lr) * QKV_N + H_ * DH_ + h * DH_ + lc;
    float4 kreg[4], vreg[4];
#pragma unroll
    for (int u = 0; u < 4; ++u) {
        kreg[u] = *(const float4*)(kbase + u * 4);
        vreg[u] = *(const float4*)(kbase + H_ * DH_ + u * 4);
    }
    float mval = (tid < 64) ? mask[b * T_ + tid] : 0.f;

    const int ntiles = blockIdx.x + 1;   // causal: tiles 0 .. qb/64
    for (int t0 = 0; t0 < ntiles; ++t0) {
        const int k0 = t0 * 64;
        // publish current tile to LDS
#pragma unroll
        for (int u = 0; u < 4; ++u) {
            *(float4*)&Ks[lr][lc + u * 4] = kreg[u];
            *(float4*)&Vs[lr][lc + u * 4] = vreg[u];
        }
        if (tid < 64) ms[tid] = mval;
        __syncthreads();

        // prefetch next tile (clamped tile index keeps loads in-bounds)
        {
            const int tn = (t0 + 1 < ntiles) ? (t0 + 1) : 0;
            const float* kn = kbase + (size_t)tn * 64 * QKV_N;
#pragma unroll
            for (int u = 0; u < 4; ++u) {
                kreg[u] = *(const float4*)(kn + u * 4);
                vreg[u] = *(const float4*)(kn + H_ * DH_ + u * 4);
            }
            mval = (tid < 64) ? mask[b * T_ + tn * 64 + tid] : 0.f;
        }

        if (k0 <= qi) {
#pragma unroll
            for (int jc = 0; jc < 4; ++jc) {
                const int jbase = jc * 16;
                if (k0 + jbase <= qi) {
                    float s[16];
#pragma unroll
                    for (int jj = 0; jj < 16; ++jj) {
                        const int j = jbase + jj;
                        const float* kr = &Ks[j][dpart];
                        float4 k0v = *(const float4*)(kr + 0);
                        float4 k1v = *(const float4*)(kr + 4);
                        float4 k2v = *(const float4*)(kr + 8);
                        float4 k3v = *(const float4*)(kr + 12);
                        float d0 = qreg[0].x * k0v.x + qreg[0].y * k0v.y +
                                   qreg[0].z * k0v.z + qreg[0].w * k0v.w;
                        float d1 = qreg[1].x * k1v.x + qreg[1].y * k1v.y +
                                   qreg[1].z * k1v.z + qreg[1].w * k1v.w;
                        float d2 = qreg[2].x * k2v.x + qreg[2].y * k2v.y +
                                   qreg[2].z * k2v.z + qreg[2].w * k2v.w;
                        float d3 = qreg[3].x * k3v.x + qreg[3].y * k3v.y +
                                   qreg[3].z * k3v.z + qreg[3].w * k3v.w;
                        float part = (d0 + d1) + (d2 + d3);
                        part += __shfl_xor(part, 1);
                        part += __shfl_xor(part, 2);
                        const int kidx = k0 + j;
                        const float am = ms[j];
                        s[jj] = (kidx <= qi && am != 0.f) ? part * scale * am
                                                          : -INFINITY;
                    }
                    float cmax = -INFINITY;
#pragma unroll
                    for (int jj = 0; jj < 16; ++jj) cmax = fmaxf(cmax, s[jj]);
                    if (cmax > -INFINITY) {
                        const float mnew = fmaxf(mrun, cmax);
                        const float corr = __expf(mrun - mnew); // exp(-inf)=0 ok
                        mrun = mnew;
                        lrun *= corr;
#pragma unroll
                        for (int u = 0; u < 4; ++u) {
                            acc[u].x *= corr; acc[u].y *= corr;
                            acc[u].z *= corr; acc[u].w *= corr;
                        }
#pragma unroll
                        for (int jj = 0; jj < 16; ++jj) {
                            const float p = __expf(s[jj] - mnew); // 0 if masked
                            lrun += p;
                            const float* vr = &Vs[jbase + jj][dpart];
#pragma unroll
                            for (int u = 0; u < 4; ++u) {
                                float4 vv = *(const float4*)(vr + u * 4);
                                acc[u].x = fmaf(p, vv.x, acc[u].x);
                                acc[u].y = fmaf(p, vv.y, acc[u].y);
                                acc[u].z = fmaf(p, vv.z, acc[u].z);
                                acc[u].w = fmaf(p, vv.w, acc[u].w);
                            }
                        }
                    }
                }
            }
        }
        __syncthreads();
    }

    const float invl = (lrun > 0.f) ? 1.f / lrun : 0.f;
    float* orow = out + (size_t)(b * T_ + qi) * (H_ * DH_) + h * DH_ + dpart;
#pragma unroll
    for (int u = 0; u < 4; ++u) {
        float4 o = acc[u];
        o.x *= invl; o.y *= invl; o.z *= invl; o.w *= invl;
        *(float4*)(orow + u * 4) = o;
    }
}

// ---------------------------------------------------------------------------
extern "C" void kernel_launch(void* const* d_in, const int* in_sizes, int n_in,
                              void* d_out, int out_size, void* d_ws, size_t ws_size,
                              hipStream_t stream)
{
    const float* x    = (const float*)d_in[0];   // [B,T,D]
    const float* Wqkv = (const float*)d_in[1];   // [D, 3*H*DH]
    const float* Wo   = (const float*)d_in[2];   // [H*DH, D]
    const float* mask = (const float*)d_in[3];   // [B,T]
    float* out = (float*)d_out;                  // [B,T,D]

    float* qkv  = (float*)d_ws;                        // [NROWS, 3072]
    float* attn = qkv + (size_t)NROWS * QKV_N;         // [NROWS, 1024]

    // 1) qkv = x @ Wqkv
    gemm_f32<<<dim3(QKV_N / 128, NROWS / 128), 256, 0, stream>>>(
        x, Wqkv, qkv, NROWS, QKV_N, D_);

    // 2) causal masked attention -> attn [b,t,H*DH]
    attn_f32<<<dim3(T_ / 64, H_, B_), 256, 0, stream>>>(qkv, mask, attn);

    // 3) out = attn @ Wo
    gemm_f32<<<dim3(D_ / 128, NROWS / 128), 256, 0, stream>>>(
        attn, Wo, out, NROWS, D_, H_ * DH_);
}

// Round 5
// 617.683 us; speedup vs baseline: 2.3271x; 2.3271x over previous
//
#include <hip/hip_runtime.h>
#include <math.h>

#define B_ 2
#define T_ 2048
#define D_ 1024
#define H_ 16
#define DH_ 64
#define NROWS (B_ * T_)        // 4096
#define QKV_N (3 * H_ * DH_)   // 3072

typedef __attribute__((ext_vector_type(8))) short short8v;  // 8 bf16
typedef __attribute__((ext_vector_type(4))) float f32x4;

// granule swizzle: XOR of a row-constant onto granule index g (0..7).
// (row>>3) term included so staging writes that share (row&7) across their
// target rows still spread across banks (fixes 8-way on Vt writes).
#define SWZ(row) ((((row) & 7) ^ (((row) >> 3) & 7)))

static __device__ __forceinline__ unsigned short f2bf(float x) {
    unsigned u = __float_as_uint(x);
    u = (u + 0x7FFFu + ((u >> 16) & 1u)) >> 16;   // RNE
    return (unsigned short)u;
}

// ---------------------------------------------------------------------------
// fp32 tiled GEMM (unchanged from round 2 — measured correct, ~89 TF).
// ---------------------------------------------------------------------------
__global__ __launch_bounds__(256)
void gemm_f32(const float* __restrict__ A, const float* __restrict__ B,
              float* __restrict__ C, int M, int N, int K)
{
    __shared__ float As[16][128];
    __shared__ float Bs[16][128];

    const int tid = threadIdx.x;
    const int bm = blockIdx.y * 128;
    const int bn = blockIdx.x * 128;
    const int tx = tid & 15;
    const int ty = tid >> 4;
    const int ar = tid >> 2;
    const int ac = (tid & 3) << 2;
    const int br = tid >> 5;
    const int bc = (tid & 31) << 2;

    const float* Ar0 = A + (size_t)(bm + ar) * K + ac;
    const float* Ar1 = A + (size_t)(bm + ar + 64) * K + ac;
    const float* Br0 = B + (size_t)br * N + bn + bc;
    const float* Br1 = B + (size_t)(br + 8) * N + bn + bc;

    float acc[8][8];
#pragma unroll
    for (int i = 0; i < 8; ++i)
#pragma unroll
        for (int j = 0; j < 8; ++j) acc[i][j] = 0.f;

    float4 a0 = *(const float4*)(Ar0);
    float4 a1 = *(const float4*)(Ar1);
    float4 b0 = *(const float4*)(Br0);
    float4 b1 = *(const float4*)(Br1);

    for (int k0 = 0; k0 < K; k0 += 16) {
        As[ac + 0][ar] = a0.x; As[ac + 1][ar] = a0.y;
        As[ac + 2][ar] = a0.z; As[ac + 3][ar] = a0.w;
        As[ac + 0][ar + 64] = a1.x; As[ac + 1][ar + 64] = a1.y;
        As[ac + 2][ar + 64] = a1.z; As[ac + 3][ar + 64] = a1.w;
        *(float4*)&Bs[br][bc] = b0;
        *(float4*)&Bs[br + 8][bc] = b1;
        __syncthreads();

        const int kn = (k0 + 16 < K) ? (k0 + 16) : 0;
        a0 = *(const float4*)(Ar0 + kn);
        a1 = *(const float4*)(Ar1 + kn);
        b0 = *(const float4*)(Br0 + (size_t)kn * N);
        b1 = *(const float4*)(Br1 + (size_t)kn * N);

#pragma unroll
        for (int kk = 0; kk < 16; ++kk) {
            float4 a0v = *(const float4*)&As[kk][ty * 4];
            float4 a1v = *(const float4*)&As[kk][64 + ty * 4];
            float4 b0v = *(const float4*)&Bs[kk][tx * 4];
            float4 b1v = *(const float4*)&Bs[kk][64 + tx * 4];
            float av[8] = {a0v.x, a0v.y, a0v.z, a0v.w, a1v.x, a1v.y, a1v.z, a1v.w};
            float bv[8] = {b0v.x, b0v.y, b0v.z, b0v.w, b1v.x, b1v.y, b1v.z, b1v.w};
#pragma unroll
            for (int i = 0; i < 8; ++i)
#pragma unroll
                for (int j = 0; j < 8; ++j)
                    acc[i][j] = fmaf(av[i], bv[j], acc[i][j]);
        }
        __syncthreads();
    }

#pragma unroll
    for (int i = 0; i < 8; ++i) {
        const int row = bm + ((i < 4) ? (ty * 4 + i) : (64 + ty * 4 + (i - 4)));
        float4 c0 = make_float4(acc[i][0], acc[i][1], acc[i][2], acc[i][3]);
        float4 c1 = make_float4(acc[i][4], acc[i][5], acc[i][6], acc[i][7]);
        *(float4*)(C + (size_t)row * N + bn + tx * 4) = c0;
        *(float4*)(C + (size_t)row * N + bn + 64 + tx * 4) = c1;
    }
}

// ---------------------------------------------------------------------------
// bf16-MFMA flash attention, fp32 softmax/accum.
// Grid: (16, H, B); block 256 = 4 waves. Block p handles q-tiles p and 31-p
// (33 k-tiles total each -> uniform work). Wave w owns 16 q-rows.
// MFMA 16x16x32 bf16: A row=l&15,k=(l>>4)*8+e; B col=l&15,k=(l>>4)*8+e;
// D row=(l>>4)*4+i, col=l&15 (m89-verified).
// LDS tiles use 16B granules XOR-swizzled by SWZ(row) (write/read symmetric).
// ---------------------------------------------------------------------------
__global__ __launch_bounds__(256)
void attn_mfma(const float* __restrict__ qkv, const float* __restrict__ mask,
               float* __restrict__ out)
{
    __shared__ unsigned short Ks[64 * 64];      // K[key][dh], swizzled granules
    __shared__ unsigned short Vt[64 * 64];      // V^T[dh][key], swizzled
    __shared__ unsigned short Pl[4][16 * 64];   // per-wave P[q][key], swizzled
    __shared__ float ms[64];

    const int tid = threadIdx.x;
    const int w   = tid >> 6;
    const int l   = tid & 63;
    const int lhi = l >> 4;        // 0..3
    const int llo = l & 15;        // 0..15
    const int b = blockIdx.z;
    const int h = blockIdx.y;

    const int sr  = tid >> 2;         // staging row 0..63
    const int sg0 = (tid & 3) * 2;    // staging granule pair

    for (int qsel = 0; qsel < 2; ++qsel) {
        const int qt = qsel ? (31 - (int)blockIdx.x) : (int)blockIdx.x;
        const int qb = qt * 64;

        // ---- Q A-frags (DH^-0.5 folded in before bf16) ----
        short8v qf[2];
        {
            const float* qrow = qkv + (size_t)(b * T_ + qb + w * 16 + llo) * QKV_N
                                + h * DH_;
#pragma unroll
            for (int kc = 0; kc < 2; ++kc) {
                const float* src = qrow + kc * 32 + lhi * 8;
                float4 c0 = *(const float4*)(src);
                float4 c1 = *(const float4*)(src + 4);
                float v[8] = {c0.x, c0.y, c0.z, c0.w, c1.x, c1.y, c1.z, c1.w};
#pragma unroll
                for (int e = 0; e < 8; ++e)
                    qf[kc][e] = (short)f2bf(v[e] * 0.125f);
            }
        }

        f32x4 acc[4];
#pragma unroll
        for (int ct = 0; ct < 4; ++ct) acc[ct] = (f32x4){0.f, 0.f, 0.f, 0.f};
        float mrow[4] = {-INFINITY, -INFINITY, -INFINITY, -INFINITY};
        float lrow[4] = {0.f, 0.f, 0.f, 0.f};

        for (int t0 = 0; t0 <= qt; ++t0) {
            const int k0 = t0 * 64;

            // ---- stage K (row-major) and V (transposed) as bf16 ----
            {
                const float* kbase = qkv + (size_t)(b * T_ + k0 + sr) * QKV_N
                                     + H_ * DH_ + h * DH_;
#pragma unroll
                for (int s = 0; s < 2; ++s) {
                    const int g = sg0 + s;
                    float4 ka = *(const float4*)(kbase + g * 8);
                    float4 kb = *(const float4*)(kbase + g * 8 + 4);
                    int4 wk;
                    wk.x = (int)((unsigned)f2bf(ka.x) | ((unsigned)f2bf(ka.y) << 16));
                    wk.y = (int)((unsigned)f2bf(ka.z) | ((unsigned)f2bf(ka.w) << 16));
                    wk.z = (int)((unsigned)f2bf(kb.x) | ((unsigned)f2bf(kb.y) << 16));
                    wk.w = (int)((unsigned)f2bf(kb.z) | ((unsigned)f2bf(kb.w) << 16));
                    *(int4*)&Ks[(sr * 8 + (g ^ SWZ(sr))) * 8] = wk;

                    float4 va = *(const float4*)(kbase + H_ * DH_ + g * 8);
                    float4 vb = *(const float4*)(kbase + H_ * DH_ + g * 8 + 4);
                    float vv[8] = {va.x, va.y, va.z, va.w, vb.x, vb.y, vb.z, vb.w};
#pragma unroll
                    for (int e = 0; e < 8; ++e) {
                        const int dr = g * 8 + e;   // Vt row = dh
                        Vt[(dr * 8 + ((sr >> 3) ^ SWZ(dr))) * 8 + (sr & 7)] =
                            f2bf(vv[e]);
                    }
                }
                if (tid < 64) ms[tid] = mask[b * T_ + k0 + tid];
            }
            __syncthreads();

            // ---- S = Qs @ K^T via MFMA ----
            float p[4][4];
#pragma unroll
            for (int ct = 0; ct < 4; ++ct) {
                f32x4 a = (f32x4){0.f, 0.f, 0.f, 0.f};
#pragma unroll
                for (int kc = 0; kc < 2; ++kc) {
                    const int row = ct * 16 + llo;      // key row
                    const int G = kc * 4 + lhi;         // dh granule
                    short8v kf = *(const short8v*)&Ks[(row * 8 + (G ^ SWZ(row))) * 8];
                    a = __builtin_amdgcn_mfma_f32_16x16x32_bf16(qf[kc], kf, a, 0, 0, 0);
                }
                const int kg = k0 + ct * 16 + llo;
                const float amv = ms[ct * 16 + llo];
#pragma unroll
                for (int i = 0; i < 4; ++i) {
                    const int qg = qb + w * 16 + lhi * 4 + i;
                    const float s = a[i] * amv;
                    p[ct][i] = (kg <= qg && amv != 0.f) ? s : -INFINITY;
                }
            }

            // ---- online softmax (rows live across 16-lane groups) ----
            float corr[4], meff[4];
#pragma unroll
            for (int i = 0; i < 4; ++i) {
                float mx = fmaxf(fmaxf(p[0][i], p[1][i]), fmaxf(p[2][i], p[3][i]));
                mx = fmaxf(mx, __shfl_xor(mx, 1));
                mx = fmaxf(mx, __shfl_xor(mx, 2));
                mx = fmaxf(mx, __shfl_xor(mx, 4));
                mx = fmaxf(mx, __shfl_xor(mx, 8));
                const float mn = fmaxf(mrow[i], mx);
                meff[i] = (mn > -INFINITY) ? mn : 0.f;
                corr[i] = __expf(mrow[i] - meff[i]);   // 0 if mrow=-inf
                mrow[i] = mn;
            }
#pragma unroll
            for (int i = 0; i < 4; ++i) {
#pragma unroll
                for (int ct = 0; ct < 4; ++ct)
                    p[ct][i] = __expf(p[ct][i] - meff[i]);  // exp(-inf)=0
                float sm = (p[0][i] + p[1][i]) + (p[2][i] + p[3][i]);
                sm += __shfl_xor(sm, 1);
                sm += __shfl_xor(sm, 2);
                sm += __shfl_xor(sm, 4);
                sm += __shfl_xor(sm, 8);
                lrow[i] = corr[i] * lrow[i] + sm;
#pragma unroll
                for (int ct2 = 0; ct2 < 4; ++ct2)
                    acc[ct2][i] *= corr[i];
            }

            // ---- P -> wave-private LDS (swizzled), read back as A-frags ----
            unsigned short* pw = Pl[w];
#pragma unroll
            for (int ct = 0; ct < 4; ++ct) {
                const int c = ct * 16 + llo;
#pragma unroll
                for (int i = 0; i < 4; ++i) {
                    const int r = lhi * 4 + i;
                    pw[(r * 8 + ((c >> 3) ^ SWZ(r))) * 8 + (c & 7)] = f2bf(p[ct][i]);
                }
            }
            asm volatile("s_waitcnt lgkmcnt(0)" ::: "memory");
            __builtin_amdgcn_sched_barrier(0);   // rule #18: pin reads after wait
            short8v pf[2];
#pragma unroll
            for (int kc = 0; kc < 2; ++kc) {
                const int G = kc * 4 + lhi;             // key granule
                pf[kc] = *(const short8v*)&pw[(llo * 8 + (G ^ SWZ(llo))) * 8];
            }

            // ---- O += P @ V via MFMA (B-frag from Vt: contiguous keys) ----
#pragma unroll
            for (int ct2 = 0; ct2 < 4; ++ct2) {
#pragma unroll
                for (int kc = 0; kc < 2; ++kc) {
                    const int row = ct2 * 16 + llo;     // Vt row = dh
                    const int G = kc * 4 + lhi;         // key granule
                    short8v vf = *(const short8v*)&Vt[(row * 8 + (G ^ SWZ(row))) * 8];
                    acc[ct2] = __builtin_amdgcn_mfma_f32_16x16x32_bf16(
                        pf[kc], vf, acc[ct2], 0, 0, 0);
                }
            }
            __syncthreads();
        }

        // ---- normalize + store fp32 ----
#pragma unroll
        for (int i = 0; i < 4; ++i) {
            const float invl = (lrow[i] > 0.f) ? 1.f / lrow[i] : 0.f;
            const int qg = qb + w * 16 + lhi * 4 + i;
            float* orow = out + (size_t)(b * T_ + qg) * (H_ * DH_) + h * DH_;
#pragma unroll
            for (int ct2 = 0; ct2 < 4; ++ct2)
                orow[ct2 * 16 + llo] = acc[ct2][i] * invl;
        }
    }
}

// ---------------------------------------------------------------------------
extern "C" void kernel_launch(void* const* d_in, const int* in_sizes, int n_in,
                              void* d_out, int out_size, void* d_ws, size_t ws_size,
                              hipStream_t stream)
{
    const float* x    = (const float*)d_in[0];
    const float* Wqkv = (const float*)d_in[1];
    const float* Wo   = (const float*)d_in[2];
    const float* mask = (const float*)d_in[3];
    float* out = (float*)d_out;

    float* qkv  = (float*)d_ws;                        // [NROWS, 3072]
    float* attn = qkv + (size_t)NROWS * QKV_N;         // [NROWS, 1024]

    gemm_f32<<<dim3(QKV_N / 128, NROWS / 128), 256, 0, stream>>>(
        x, Wqkv, qkv, NROWS, QKV_N, D_);

    attn_mfma<<<dim3(16, H_, B_), 256, 0, stream>>>(qkv, mask, attn);

    gemm_f32<<<dim3(D_ / 128, NROWS / 128), 256, 0, stream>>>(
        attn, Wo, out, NROWS, D_, H_ * DH_);
}

// Round 6
// 251.432 us; speedup vs baseline: 5.7169x; 2.4567x over previous
//
#include <hip/hip_runtime.h>
#include <math.h>

#define B_ 2
#define T_ 2048
#define D_ 1024
#define H_ 16
#define DH_ 64
#define NROWS (B_ * T_)        // 4096
#define QKV_N (3 * H_ * DH_)   // 3072

typedef __attribute__((ext_vector_type(8))) short short8v;  // 8 bf16
typedef __attribute__((ext_vector_type(4))) float f32x4;

// attention LDS granule swizzle (round-5, measured-correct)
#define SWZ(row) ((((row) & 7) ^ (((row) >> 3) & 7)))
// GEMM LDS granule swizzle: rows stride 64B (4 granules); lane-enumerated
// conflict-free for both staging writes and b128 frag reads.
#define GSWZ(row) (((row) >> 1) & 3)

static __device__ __forceinline__ unsigned short f2bf(float x) {
    unsigned u = __float_as_uint(x);
    u = (u + 0x7FFFu + ((u >> 16) & 1u)) >> 16;   // RNE
    return (unsigned short)u;
}
static __device__ __forceinline__ int packbf(float lo, float hi) {
    return (int)((unsigned)f2bf(lo) | ((unsigned)f2bf(hi) << 16));
}

// ---------------------------------------------------------------------------
// fp32 -> bf16 straight conversion (vectorized, 8 elems/thread)
// ---------------------------------------------------------------------------
__global__ __launch_bounds__(256)
void f32_to_bf16_k(const float* __restrict__ in, unsigned short* __restrict__ out,
                   int n8)
{
    const int i = blockIdx.x * 256 + threadIdx.x;
    if (i >= n8) return;
    const float4* p = (const float4*)in;
    float4 a = p[2 * i], b = p[2 * i + 1];
    int4 w;
    w.x = packbf(a.x, a.y); w.y = packbf(a.z, a.w);
    w.z = packbf(b.x, b.y); w.w = packbf(b.z, b.w);
    ((int4*)out)[i] = w;
}

// ---------------------------------------------------------------------------
// fp32 [R][C] -> bf16 [C][R] transpose-convert. 64x64 tiles, padded LDS.
// ---------------------------------------------------------------------------
__global__ __launch_bounds__(256)
void transpose_bf16_k(const float* __restrict__ in, unsigned short* __restrict__ out,
                      int R, int C)
{
    __shared__ float tile[64][65];
    const int r0 = blockIdx.y * 64, c0 = blockIdx.x * 64;
    const int tr = threadIdx.x >> 4;          // 0..15
    const int tc = (threadIdx.x & 15) * 4;    // 0..60
#pragma unroll
    for (int rr = 0; rr < 64; rr += 16) {
        float4 v = *(const float4*)(in + (size_t)(r0 + tr + rr) * C + c0 + tc);
        tile[tr + rr][tc + 0] = v.x; tile[tr + rr][tc + 1] = v.y;
        tile[tr + rr][tc + 2] = v.z; tile[tr + rr][tc + 3] = v.w;
    }
    __syncthreads();
    const int ow = threadIdx.x >> 2;          // out row (c idx) 0..63
    const int os = (threadIdx.x & 3) * 16;    // 16 elems along r
    int4 w0, w1;
    float s[16];
#pragma unroll
    for (int e = 0; e < 16; ++e) s[e] = tile[os + e][ow];
    w0.x = packbf(s[0], s[1]);   w0.y = packbf(s[2], s[3]);
    w0.z = packbf(s[4], s[5]);   w0.w = packbf(s[6], s[7]);
    w1.x = packbf(s[8], s[9]);   w1.y = packbf(s[10], s[11]);
    w1.z = packbf(s[12], s[13]); w1.w = packbf(s[14], s[15]);
    unsigned short* orow = out + (size_t)(c0 + ow) * R + r0 + os;
    *(int4*)(orow) = w0;
    *(int4*)(orow + 8) = w1;
}

// ---------------------------------------------------------------------------
// bf16 MFMA GEMM: C_f32[M][N] = A_bf16[M][K] @ Bt_bf16[N][K]^T.
// 128x128 tile, BK=32, 256 thr = 4 waves (2x2), 4x4 16x16x32 frags/wave.
// Reg-staged double-buffered LDS; granule swizzle GSWZ -> conflict-free
// staging writes AND frag b128 reads. Requires M%128==N%128==0, K%32==0.
// ---------------------------------------------------------------------------
__global__ __launch_bounds__(256)
void gemm_bt_bf16(const unsigned short* __restrict__ A,
                  const unsigned short* __restrict__ Bt,
                  float* __restrict__ C, int M, int N, int K)
{
    __shared__ __align__(16) unsigned short As[2][128 * 32];
    __shared__ __align__(16) unsigned short Bs[2][128 * 32];

    const int tid = threadIdx.x;
    const int w = tid >> 6, l = tid & 63;
    const int lhi = l >> 4, llo = l & 15;
    const int wr = w >> 1, wc = w & 1;
    const int bm = blockIdx.y * 128, bn = blockIdx.x * 128;

    const int srow = w * 32 + (l >> 2);   // staging rows: srow, srow+16
    const int sg   = l & 3;               // logical 16B granule in row

    const unsigned short* Ab = A + (size_t)bm * K;
    const unsigned short* Bb = Bt + (size_t)bn * K;

    f32x4 acc[4][4];
#pragma unroll
    for (int mi = 0; mi < 4; ++mi)
#pragma unroll
        for (int ni = 0; ni < 4; ++ni) acc[mi][ni] = (f32x4){0.f, 0.f, 0.f, 0.f};

    short8v a0r, a1r, b0r, b1r;
    const int nt = K >> 5;

#define LOADT(t) do {                                                        \
        const size_t ko = (size_t)(t) * 32 + sg * 8;                         \
        a0r = *(const short8v*)(Ab + (size_t)srow * K + ko);                 \
        a1r = *(const short8v*)(Ab + (size_t)(srow + 16) * K + ko);         \
        b0r = *(const short8v*)(Bb + (size_t)srow * K + ko);                 \
        b1r = *(const short8v*)(Bb + (size_t)(srow + 16) * K + ko);         \
    } while (0)
#define WRITET(buf) do {                                                     \
        *(short8v*)&As[buf][srow * 32 + (sg ^ GSWZ(srow)) * 8] = a0r;        \
        *(short8v*)&As[buf][(srow + 16) * 32 + (sg ^ GSWZ(srow + 16)) * 8] = a1r; \
        *(short8v*)&Bs[buf][srow * 32 + (sg ^ GSWZ(srow)) * 8] = b0r;        \
        *(short8v*)&Bs[buf][(srow + 16) * 32 + (sg ^ GSWZ(srow + 16)) * 8] = b1r; \
    } while (0)

    LOADT(0);
    WRITET(0);
    __syncthreads();

    int cur = 0;
    for (int t = 0; t < nt; ++t) {
        if (t + 1 < nt) LOADT(t + 1);

        short8v af[4], bf[4];
#pragma unroll
        for (int mi = 0; mi < 4; ++mi) {
            const int m = wr * 64 + mi * 16 + llo;
            af[mi] = *(const short8v*)&As[cur][m * 32 + (lhi ^ GSWZ(m)) * 8];
        }
#pragma unroll
        for (int ni = 0; ni < 4; ++ni) {
            const int n = wc * 64 + ni * 16 + llo;
            bf[ni] = *(const short8v*)&Bs[cur][n * 32 + (lhi ^ GSWZ(n)) * 8];
        }
#pragma unroll
        for (int mi = 0; mi < 4; ++mi)
#pragma unroll
            for (int ni = 0; ni < 4; ++ni)
                acc[mi][ni] = __builtin_amdgcn_mfma_f32_16x16x32_bf16(
                    af[mi], bf[ni], acc[mi][ni], 0, 0, 0);

        if (t + 1 < nt) WRITET(cur ^ 1);
        __syncthreads();
        cur ^= 1;
    }
#undef LOADT
#undef WRITET

    // epilogue: D row=(l>>4)*4+i, col=l&15 (m89-verified)
#pragma unroll
    for (int mi = 0; mi < 4; ++mi)
#pragma unroll
        for (int ni = 0; ni < 4; ++ni) {
            const int col = bn + wc * 64 + ni * 16 + llo;
            const int rb = bm + wr * 64 + mi * 16 + lhi * 4;
#pragma unroll
            for (int i = 0; i < 4; ++i)
                C[(size_t)(rb + i) * N + col] = acc[mi][ni][i];
        }
}

// ---------------------------------------------------------------------------
// bf16-MFMA flash attention (round-5, measured 197us) — epilogue now bf16.
// ---------------------------------------------------------------------------
__global__ __launch_bounds__(256)
void attn_mfma(const float* __restrict__ qkv, const float* __restrict__ mask,
               unsigned short* __restrict__ out)
{
    __shared__ __align__(16) unsigned short Ks[64 * 64];
    __shared__ __align__(16) unsigned short Vt[64 * 64];
    __shared__ __align__(16) unsigned short Pl[4][16 * 64];
    __shared__ float ms[64];

    const int tid = threadIdx.x;
    const int w   = tid >> 6;
    const int l   = tid & 63;
    const int lhi = l >> 4;
    const int llo = l & 15;
    const int b = blockIdx.z;
    const int h = blockIdx.y;

    const int sr  = tid >> 2;
    const int sg0 = (tid & 3) * 2;

    for (int qsel = 0; qsel < 2; ++qsel) {
        const int qt = qsel ? (31 - (int)blockIdx.x) : (int)blockIdx.x;
        const int qb = qt * 64;

        short8v qf[2];
        {
            const float* qrow = qkv + (size_t)(b * T_ + qb + w * 16 + llo) * QKV_N
                                + h * DH_;
#pragma unroll
            for (int kc = 0; kc < 2; ++kc) {
                const float* src = qrow + kc * 32 + lhi * 8;
                float4 c0 = *(const float4*)(src);
                float4 c1 = *(const float4*)(src + 4);
                float v[8] = {c0.x, c0.y, c0.z, c0.w, c1.x, c1.y, c1.z, c1.w};
#pragma unroll
                for (int e = 0; e < 8; ++e)
                    qf[kc][e] = (short)f2bf(v[e] * 0.125f);
            }
        }

        f32x4 acc[4];
#pragma unroll
        for (int ct = 0; ct < 4; ++ct) acc[ct] = (f32x4){0.f, 0.f, 0.f, 0.f};
        float mrow[4] = {-INFINITY, -INFINITY, -INFINITY, -INFINITY};
        float lrow[4] = {0.f, 0.f, 0.f, 0.f};

        for (int t0 = 0; t0 <= qt; ++t0) {
            const int k0 = t0 * 64;
            {
                const float* kbase = qkv + (size_t)(b * T_ + k0 + sr) * QKV_N
                                     + H_ * DH_ + h * DH_;
#pragma unroll
                for (int s = 0; s < 2; ++s) {
                    const int g = sg0 + s;
                    float4 ka = *(const float4*)(kbase + g * 8);
                    float4 kb = *(const float4*)(kbase + g * 8 + 4);
                    int4 wk;
                    wk.x = packbf(ka.x, ka.y); wk.y = packbf(ka.z, ka.w);
                    wk.z = packbf(kb.x, kb.y); wk.w = packbf(kb.z, kb.w);
                    *(int4*)&Ks[(sr * 8 + (g ^ SWZ(sr))) * 8] = wk;

                    float4 va = *(const float4*)(kbase + H_ * DH_ + g * 8);
                    float4 vb = *(const float4*)(kbase + H_ * DH_ + g * 8 + 4);
                    float vv[8] = {va.x, va.y, va.z, va.w, vb.x, vb.y, vb.z, vb.w};
#pragma unroll
                    for (int e = 0; e < 8; ++e) {
                        const int dr = g * 8 + e;
                        Vt[(dr * 8 + ((sr >> 3) ^ SWZ(dr))) * 8 + (sr & 7)] =
                            f2bf(vv[e]);
                    }
                }
                if (tid < 64) ms[tid] = mask[b * T_ + k0 + tid];
            }
            __syncthreads();

            float p[4][4];
#pragma unroll
            for (int ct = 0; ct < 4; ++ct) {
                f32x4 a = (f32x4){0.f, 0.f, 0.f, 0.f};
#pragma unroll
                for (int kc = 0; kc < 2; ++kc) {
                    const int row = ct * 16 + llo;
                    const int G = kc * 4 + lhi;
                    short8v kf = *(const short8v*)&Ks[(row * 8 + (G ^ SWZ(row))) * 8];
                    a = __builtin_amdgcn_mfma_f32_16x16x32_bf16(qf[kc], kf, a, 0, 0, 0);
                }
                const int kg = k0 + ct * 16 + llo;
                const float amv = ms[ct * 16 + llo];
#pragma unroll
                for (int i = 0; i < 4; ++i) {
                    const int qg = qb + w * 16 + lhi * 4 + i;
                    const float s = a[i] * amv;
                    p[ct][i] = (kg <= qg && amv != 0.f) ? s : -INFINITY;
                }
            }

            float corr[4], meff[4];
#pragma unroll
            for (int i = 0; i < 4; ++i) {
                float mx = fmaxf(fmaxf(p[0][i], p[1][i]), fmaxf(p[2][i], p[3][i]));
                mx = fmaxf(mx, __shfl_xor(mx, 1));
                mx = fmaxf(mx, __shfl_xor(mx, 2));
                mx = fmaxf(mx, __shfl_xor(mx, 4));
                mx = fmaxf(mx, __shfl_xor(mx, 8));
                const float mn = fmaxf(mrow[i], mx);
                meff[i] = (mn > -INFINITY) ? mn : 0.f;
                corr[i] = __expf(mrow[i] - meff[i]);
                mrow[i] = mn;
            }
#pragma unroll
            for (int i = 0; i < 4; ++i) {
#pragma unroll
                for (int ct = 0; ct < 4; ++ct)
                    p[ct][i] = __expf(p[ct][i] - meff[i]);
                float sm = (p[0][i] + p[1][i]) + (p[2][i] + p[3][i]);
                sm += __shfl_xor(sm, 1);
                sm += __shfl_xor(sm, 2);
                sm += __shfl_xor(sm, 4);
                sm += __shfl_xor(sm, 8);
                lrow[i] = corr[i] * lrow[i] + sm;
#pragma unroll
                for (int ct2 = 0; ct2 < 4; ++ct2)
                    acc[ct2][i] *= corr[i];
            }

            unsigned short* pw = Pl[w];
#pragma unroll
            for (int ct = 0; ct < 4; ++ct) {
                const int c = ct * 16 + llo;
#pragma unroll
                for (int i = 0; i < 4; ++i) {
                    const int r = lhi * 4 + i;
                    pw[(r * 8 + ((c >> 3) ^ SWZ(r))) * 8 + (c & 7)] = f2bf(p[ct][i]);
                }
            }
            asm volatile("s_waitcnt lgkmcnt(0)" ::: "memory");
            __builtin_amdgcn_sched_barrier(0);
            short8v pf[2];
#pragma unroll
            for (int kc = 0; kc < 2; ++kc) {
                const int G = kc * 4 + lhi;
                pf[kc] = *(const short8v*)&pw[(llo * 8 + (G ^ SWZ(llo))) * 8];
            }

#pragma unroll
            for (int ct2 = 0; ct2 < 4; ++ct2) {
#pragma unroll
                for (int kc = 0; kc < 2; ++kc) {
                    const int row = ct2 * 16 + llo;
                    const int G = kc * 4 + lhi;
                    short8v vf = *(const short8v*)&Vt[(row * 8 + (G ^ SWZ(row))) * 8];
                    acc[ct2] = __builtin_amdgcn_mfma_f32_16x16x32_bf16(
                        pf[kc], vf, acc[ct2], 0, 0, 0);
                }
            }
            __syncthreads();
        }

#pragma unroll
        for (int i = 0; i < 4; ++i) {
            const float invl = (lrow[i] > 0.f) ? 1.f / lrow[i] : 0.f;
            const int qg = qb + w * 16 + lhi * 4 + i;
            unsigned short* orow = out + (size_t)(b * T_ + qg) * (H_ * DH_) + h * DH_;
#pragma unroll
            for (int ct2 = 0; ct2 < 4; ++ct2)
                orow[ct2 * 16 + llo] = f2bf(acc[ct2][i] * invl);
        }
    }
}

// ---------------------------------------------------------------------------
extern "C" void kernel_launch(void* const* d_in, const int* in_sizes, int n_in,
                              void* d_out, int out_size, void* d_ws, size_t ws_size,
                              hipStream_t stream)
{
    const float* x    = (const float*)d_in[0];   // [B,T,D]
    const float* Wqkv = (const float*)d_in[1];   // [D, 3*H*DH]
    const float* Wo   = (const float*)d_in[2];   // [H*DH, D]
    const float* mask = (const float*)d_in[3];   // [B,T]
    float* out = (float*)d_out;                  // [B,T,D] fp32

    // workspace layout (75.5 MB)
    char* p = (char*)d_ws;
    float* qkv = (float*)p;                 p += (size_t)NROWS * QKV_N * 4;
    unsigned short* xb      = (unsigned short*)p; p += (size_t)NROWS * D_ * 2;
    unsigned short* wqkv_t  = (unsigned short*)p; p += (size_t)QKV_N * D_ * 2;
    unsigned short* wo_t    = (unsigned short*)p; p += (size_t)D_ * D_ * 2;
    unsigned short* attnb   = (unsigned short*)p;

    // 0) conversions
    f32_to_bf16_k<<<(NROWS * D_ / 8 + 255) / 256, 256, 0, stream>>>(
        x, xb, NROWS * D_ / 8);
    transpose_bf16_k<<<dim3(QKV_N / 64, D_ / 64), 256, 0, stream>>>(
        Wqkv, wqkv_t, D_, QKV_N);
    transpose_bf16_k<<<dim3(D_ / 64, D_ / 64), 256, 0, stream>>>(
        Wo, wo_t, D_, D_);

    // 1) qkv = x @ Wqkv  (bf16 MFMA, fp32 out)
    gemm_bt_bf16<<<dim3(QKV_N / 128, NROWS / 128), 256, 0, stream>>>(
        xb, wqkv_t, qkv, NROWS, QKV_N, D_);

    // 2) attention -> attnb (bf16)
    attn_mfma<<<dim3(16, H_, B_), 256, 0, stream>>>(qkv, mask, attnb);

    // 3) out = attn @ Wo  (bf16 MFMA, fp32 out)
    gemm_bt_bf16<<<dim3(D_ / 128, NROWS / 128), 256, 0, stream>>>(
        attnb, wo_t, out, NROWS, D_, H_ * DH_);
}